// Round 1
// baseline (599.858 us; speedup 1.0000x reference)
//
#include <hip/hip_runtime.h>
#include <hip/hip_bf16.h>

#define NNODES 100000
#define HID 256
#define NMOVES 500000
#define NGRAPHS 512

typedef __attribute__((ext_vector_type(8))) short short8;
typedef __attribute__((ext_vector_type(4))) float f32x4;

__device__ __forceinline__ ushort f2bf(float f) {
    unsigned u = __builtin_bit_cast(unsigned, f);
    u += 0x7FFFu + ((u >> 16) & 1u);   // round-to-nearest-even
    return (ushort)(u >> 16);
}
__device__ __forceinline__ float bf2f(ushort h) {
    unsigned u = ((unsigned)h) << 16;
    return __builtin_bit_cast(float, u);
}
// order-preserving float<->uint encoding for atomicMax
__device__ __forceinline__ unsigned encf(float f) {
    unsigned b = __builtin_bit_cast(unsigned, f);
    return (b & 0x80000000u) ? ~b : (b ^ 0x80000000u);
}
__device__ __forceinline__ float decf(unsigned u) {
    unsigned b = (u & 0x80000000u) ? (u ^ 0x80000000u) : ~u;
    return __builtin_bit_cast(float, b);
}

// ---- convert node embeddings f32 -> bf16, 8 elems/thread ----
__global__ void k_convert_emb(const float* __restrict__ src, ushort* __restrict__ dst, int total8) {
    int t = blockIdx.x * blockDim.x + threadIdx.x;
    if (t >= total8) return;
    float4 v0 = reinterpret_cast<const float4*>(src)[2 * t];
    float4 v1 = reinterpret_cast<const float4*>(src)[2 * t + 1];
    uint4 o;
    o.x = (unsigned)f2bf(v0.x) | ((unsigned)f2bf(v0.y) << 16);
    o.y = (unsigned)f2bf(v0.z) | ((unsigned)f2bf(v0.w) << 16);
    o.z = (unsigned)f2bf(v1.x) | ((unsigned)f2bf(v1.y) << 16);
    o.w = (unsigned)f2bf(v1.z) | ((unsigned)f2bf(v1.w) << 16);
    reinterpret_cast<uint4*>(dst)[t] = o;
}

// ---- build W1' transposed: W1t[n][k] (n=0..511 output col, k=0..255) ----
// col n<256  -> W1[k, n]        (applies to emb[src])
// col n>=256 -> W1[256+k, n-256] (applies to emb[tgt])
__global__ void k_convert_w1(const float* __restrict__ W1, ushort* __restrict__ W1t) {
    int t = blockIdx.x * blockDim.x + threadIdx.x; // 131072
    int n = t >> 8, k = t & 255;
    float v = (n < 256) ? W1[k * 256 + n] : W1[(k + 256) * 256 + (n - 256)];
    W1t[t] = f2bf(v);
}

__global__ void k_init(unsigned* __restrict__ segmax, float* __restrict__ segsum) {
    int t = threadIdx.x; // 512 threads
    segmax[t] = 0u;      // == encf(most negative); only read for non-empty segments
    segsum[t] = 0.f;
}

// ---- P[m][n] = sum_k Ebf[m][k] * W1t[n][k], bf16 in / bf16 out, f32 acc ----
__global__ __launch_bounds__(256) void k_gemm(const ushort* __restrict__ A,
                                              const ushort* __restrict__ Bt,
                                              ushort* __restrict__ P, int M) {
    __shared__ ushort As[128][40]; // +8 pad keeps 16B align, breaks bank conflicts
    __shared__ ushort Bs[128][40];
    int bid = blockIdx.x;
    int tm = (bid >> 2) * 128;
    int tn = (bid & 3) * 128;
    int tid = threadIdx.x;
    int lane = tid & 63;
    int wave = tid >> 6;
    int wr = (wave >> 1) * 64;
    int wc = (wave & 1) * 64;

    f32x4 acc[4][4];
#pragma unroll
    for (int m = 0; m < 4; ++m)
#pragma unroll
        for (int n = 0; n < 4; ++n) acc[m][n] = (f32x4){0.f, 0.f, 0.f, 0.f};

    int r = tid >> 1;          // staging row 0..127
    int cc = (tid & 1) * 16;   // staging col offset (elements)

    for (int kt = 0; kt < HID; kt += 32) {
        uint4 va0 = {0, 0, 0, 0}, va1 = {0, 0, 0, 0};
        int grow = tm + r;
        if (grow < M) {
            const uint4* ga = reinterpret_cast<const uint4*>(A + grow * 256 + kt + cc);
            va0 = ga[0]; va1 = ga[1];
        }
        const uint4* gb = reinterpret_cast<const uint4*>(Bt + (tn + r) * 256 + kt + cc);
        uint4 vb0 = gb[0], vb1 = gb[1];
        __syncthreads(); // previous iter's reads done before overwrite
        *reinterpret_cast<uint4*>(&As[r][cc]) = va0;
        *reinterpret_cast<uint4*>(&As[r][cc + 8]) = va1;
        *reinterpret_cast<uint4*>(&Bs[r][cc]) = vb0;
        *reinterpret_cast<uint4*>(&Bs[r][cc + 8]) = vb1;
        __syncthreads();

        int fr = lane & 15;
        int kc = (lane >> 4) * 8;
        short8 af[4], bfv[4];
#pragma unroll
        for (int m = 0; m < 4; ++m)
            af[m] = *reinterpret_cast<const short8*>(&As[wr + m * 16 + fr][kc]);
#pragma unroll
        for (int n = 0; n < 4; ++n)
            bfv[n] = *reinterpret_cast<const short8*>(&Bs[wc + n * 16 + fr][kc]);
#pragma unroll
        for (int m = 0; m < 4; ++m)
#pragma unroll
            for (int n = 0; n < 4; ++n)
                acc[m][n] = __builtin_amdgcn_mfma_f32_16x16x32_bf16(af[m], bfv[n], acc[m][n], 0, 0, 0);
    }

    // C/D layout: col = lane&15, row = (lane>>4)*4 + j
    int fr = lane & 15;
    int rj = (lane >> 4) * 4;
#pragma unroll
    for (int m = 0; m < 4; ++m) {
#pragma unroll
        for (int n = 0; n < 4; ++n) {
            int col = tn + wc + n * 16 + fr;
            int rowb = tm + wr + m * 16 + rj;
#pragma unroll
            for (int j = 0; j < 4; ++j) {
                int rr = rowb + j;
                if (rr < M) P[(size_t)rr * 512 + col] = f2bf(acc[m][n][j]);
            }
        }
    }
}

// ---- per-move: h = relu(P[s][0:256] + P[t][256:512] + b1); logit = h.W2 + b2 ----
__global__ __launch_bounds__(256) void k_moves(const int* __restrict__ srcs,
                                               const int* __restrict__ tgts,
                                               const int* __restrict__ batch,
                                               const ushort* __restrict__ P,
                                               const float* __restrict__ b1,
                                               const float* __restrict__ W2,
                                               const float* __restrict__ b2,
                                               float* __restrict__ logits,
                                               int* __restrict__ mb,
                                               unsigned* __restrict__ segmax) {
    int lane = threadIdx.x & 63;
    int wid = (blockIdx.x * blockDim.x + threadIdx.x) >> 6;
    int nw = (gridDim.x * blockDim.x) >> 6;
    float4 b1v = reinterpret_cast<const float4*>(b1)[lane];
    float4 w2v = reinterpret_cast<const float4*>(W2)[lane];
    float b2s = b2[0];
    for (int m = wid; m < NMOVES; m += nw) {
        int s = srcs[m];
        int t = tgts[m];
        ushort4 a4 = *reinterpret_cast<const ushort4*>(P + (size_t)s * 512 + lane * 4);
        ushort4 b4 = *reinterpret_cast<const ushort4*>(P + (size_t)t * 512 + 256 + lane * 4);
        float h0 = fmaxf(bf2f(a4.x) + bf2f(b4.x) + b1v.x, 0.f);
        float h1 = fmaxf(bf2f(a4.y) + bf2f(b4.y) + b1v.y, 0.f);
        float h2 = fmaxf(bf2f(a4.z) + bf2f(b4.z) + b1v.z, 0.f);
        float h3 = fmaxf(bf2f(a4.w) + bf2f(b4.w) + b1v.w, 0.f);
        float partial = h0 * w2v.x + h1 * w2v.y + h2 * w2v.z + h3 * w2v.w;
#pragma unroll
        for (int off = 32; off; off >>= 1) partial += __shfl_xor(partial, off);
        if (lane == 0) {
            float logit = partial + b2s;
            logits[m] = logit;
            int g = batch[s];
            mb[m] = g;
            atomicMax(&segmax[g], encf(logit));
        }
    }
}

__global__ void k_exp(float* __restrict__ logits, const int* __restrict__ mb,
                      const unsigned* __restrict__ segmax, float* __restrict__ segsum) {
    int i = blockIdx.x * blockDim.x + threadIdx.x;
    int n = gridDim.x * blockDim.x;
    for (int m = i; m < NMOVES; m += n) {
        int g = mb[m];
        float ex = __expf(logits[m] - decf(segmax[g]));
        logits[m] = ex; // overwrite with exp'd value
        atomicAdd(&segsum[g], ex);
    }
}

__global__ void k_norm(const float* __restrict__ ex, const int* __restrict__ mb,
                       const float* __restrict__ segsum, float* __restrict__ out) {
    int i = blockIdx.x * blockDim.x + threadIdx.x;
    int n = gridDim.x * blockDim.x;
    for (int m = i; m < NMOVES; m += n) {
        out[m] = ex[m] / (segsum[mb[m]] + 1e-16f);
    }
}

extern "C" void kernel_launch(void* const* d_in, const int* in_sizes, int n_in,
                              void* d_out, int out_size, void* d_ws, size_t ws_size,
                              hipStream_t stream) {
    const float* emb = (const float*)d_in[0];
    const int* moves = (const int*)d_in[1];   // [2, 500000]
    const int* batch = (const int*)d_in[2];   // [100000]
    const float* W1 = (const float*)d_in[3];  // [512,256]
    const float* b1 = (const float*)d_in[4];  // [256]
    const float* W2 = (const float*)d_in[5];  // [256]
    const float* b2 = (const float*)d_in[6];  // [1]
    float* out = (float*)d_out;

    auto al = [](size_t x) { return (x + 255) & ~(size_t)255; };
    char* ws = (char*)d_ws;
    size_t off = 0;
    ushort* Ebf = (ushort*)(ws + off); off += al((size_t)NNODES * HID * 2);      // 51.2 MB
    ushort* W1t = (ushort*)(ws + off); off += al((size_t)512 * 256 * 2);         // 0.26 MB
    ushort* P   = (ushort*)(ws + off); off += al((size_t)NNODES * 512 * 2);      // 102.4 MB
    float* logits = (float*)(ws + off); off += al((size_t)NMOVES * 4);           // 2 MB
    int* mb       = (int*)(ws + off);   off += al((size_t)NMOVES * 4);           // 2 MB
    unsigned* segmax = (unsigned*)(ws + off); off += al((size_t)NGRAPHS * 4);
    float* segsum    = (float*)(ws + off);    off += al((size_t)NGRAPHS * 4);

    k_convert_emb<<<(NNODES * HID / 8 + 255) / 256, 256, 0, stream>>>(emb, Ebf, NNODES * HID / 8);
    k_convert_w1<<<512, 256, 0, stream>>>(W1, W1t);
    k_init<<<1, 512, 0, stream>>>(segmax, segsum);

    int tiles_m = (NNODES + 127) / 128;
    k_gemm<<<tiles_m * 4, 256, 0, stream>>>(Ebf, W1t, P, NNODES);

    k_moves<<<2048, 256, 0, stream>>>(moves, moves + NMOVES, batch, P, b1, W2, b2,
                                      logits, mb, segmax);
    k_exp<<<1024, 256, 0, stream>>>(logits, mb, segmax, segsum);
    k_norm<<<1024, 256, 0, stream>>>(logits, mb, segsum, out);
}

// Round 2
// 584.906 us; speedup vs baseline: 1.0256x; 1.0256x over previous
//
#include <hip/hip_runtime.h>
#include <hip/hip_bf16.h>

#define NNODES 100000
#define HID 256
#define NMOVES 500000
#define NGRAPHS 512

typedef __attribute__((ext_vector_type(8))) short short8;
typedef __attribute__((ext_vector_type(4))) float f32x4;

__device__ __forceinline__ ushort f2bf(float f) {
    unsigned u = __builtin_bit_cast(unsigned, f);
    u += 0x7FFFu + ((u >> 16) & 1u);   // round-to-nearest-even
    return (ushort)(u >> 16);
}
__device__ __forceinline__ float bf2f(ushort h) {
    unsigned u = ((unsigned)h) << 16;
    return __builtin_bit_cast(float, u);
}
// order-preserving float<->uint encoding for atomicMax
__device__ __forceinline__ unsigned encf(float f) {
    unsigned b = __builtin_bit_cast(unsigned, f);
    return (b & 0x80000000u) ? ~b : (b ^ 0x80000000u);
}
__device__ __forceinline__ float decf(unsigned u) {
    unsigned b = (u & 0x80000000u) ? (u ^ 0x80000000u) : ~u;
    return __builtin_bit_cast(float, b);
}

// ---- convert node embeddings f32 -> bf16, 8 elems/thread ----
__global__ void k_convert_emb(const float* __restrict__ src, ushort* __restrict__ dst, int total8) {
    int t = blockIdx.x * blockDim.x + threadIdx.x;
    if (t >= total8) return;
    float4 v0 = reinterpret_cast<const float4*>(src)[2 * t];
    float4 v1 = reinterpret_cast<const float4*>(src)[2 * t + 1];
    uint4 o;
    o.x = (unsigned)f2bf(v0.x) | ((unsigned)f2bf(v0.y) << 16);
    o.y = (unsigned)f2bf(v0.z) | ((unsigned)f2bf(v0.w) << 16);
    o.z = (unsigned)f2bf(v1.x) | ((unsigned)f2bf(v1.y) << 16);
    o.w = (unsigned)f2bf(v1.z) | ((unsigned)f2bf(v1.w) << 16);
    reinterpret_cast<uint4*>(dst)[t] = o;
}

// ---- build W1' transposed: W1t[n][k] (n=0..511 output col, k=0..255) ----
__global__ void k_convert_w1(const float* __restrict__ W1, ushort* __restrict__ W1t) {
    int t = blockIdx.x * blockDim.x + threadIdx.x; // 131072
    int n = t >> 8, k = t & 255;
    float v = (n < 256) ? W1[k * 256 + n] : W1[(k + 256) * 256 + (n - 256)];
    W1t[t] = f2bf(v);
}

__global__ void k_init(unsigned* __restrict__ segmax, float* __restrict__ segsum) {
    int t = threadIdx.x; // 512 threads
    segmax[t] = 0u;
    segsum[t] = 0.f;
}

// ---- P[m][n] = sum_k Ebf[m][k] * W1t[n][k], bf16 in / bf16 out, f32 acc ----
__global__ __launch_bounds__(256) void k_gemm(const ushort* __restrict__ A,
                                              const ushort* __restrict__ Bt,
                                              ushort* __restrict__ P, int M) {
    __shared__ ushort As[128][40];
    __shared__ ushort Bs[128][40];
    int bid = blockIdx.x;
    int tm = (bid >> 2) * 128;
    int tn = (bid & 3) * 128;
    int tid = threadIdx.x;
    int lane = tid & 63;
    int wave = tid >> 6;
    int wr = (wave >> 1) * 64;
    int wc = (wave & 1) * 64;

    f32x4 acc[4][4];
#pragma unroll
    for (int m = 0; m < 4; ++m)
#pragma unroll
        for (int n = 0; n < 4; ++n) acc[m][n] = (f32x4){0.f, 0.f, 0.f, 0.f};

    int r = tid >> 1;
    int cc = (tid & 1) * 16;

    for (int kt = 0; kt < HID; kt += 32) {
        uint4 va0 = {0, 0, 0, 0}, va1 = {0, 0, 0, 0};
        int grow = tm + r;
        if (grow < M) {
            const uint4* ga = reinterpret_cast<const uint4*>(A + grow * 256 + kt + cc);
            va0 = ga[0]; va1 = ga[1];
        }
        const uint4* gb = reinterpret_cast<const uint4*>(Bt + (tn + r) * 256 + kt + cc);
        uint4 vb0 = gb[0], vb1 = gb[1];
        __syncthreads();
        *reinterpret_cast<uint4*>(&As[r][cc]) = va0;
        *reinterpret_cast<uint4*>(&As[r][cc + 8]) = va1;
        *reinterpret_cast<uint4*>(&Bs[r][cc]) = vb0;
        *reinterpret_cast<uint4*>(&Bs[r][cc + 8]) = vb1;
        __syncthreads();

        int fr = lane & 15;
        int kc = (lane >> 4) * 8;
        short8 af[4], bfv[4];
#pragma unroll
        for (int m = 0; m < 4; ++m)
            af[m] = *reinterpret_cast<const short8*>(&As[wr + m * 16 + fr][kc]);
#pragma unroll
        for (int n = 0; n < 4; ++n)
            bfv[n] = *reinterpret_cast<const short8*>(&Bs[wc + n * 16 + fr][kc]);
#pragma unroll
        for (int m = 0; m < 4; ++m)
#pragma unroll
            for (int n = 0; n < 4; ++n)
                acc[m][n] = __builtin_amdgcn_mfma_f32_16x16x32_bf16(af[m], bfv[n], acc[m][n], 0, 0, 0);
    }

    int fr = lane & 15;
    int rj = (lane >> 4) * 4;
#pragma unroll
    for (int m = 0; m < 4; ++m) {
#pragma unroll
        for (int n = 0; n < 4; ++n) {
            int col = tn + wc + n * 16 + fr;
            int rowb = tm + wr + m * 16 + rj;
#pragma unroll
            for (int j = 0; j < 4; ++j) {
                int rr = rowb + j;
                if (rr < M) P[(size_t)rr * 512 + col] = f2bf(acc[m][n][j]);
            }
        }
    }
}

// ---- per-move MLP tail: 16 lanes/move, 4 moves/wave, unroll x2 ----
__device__ __forceinline__ float dot8(uint4 a, uint4 b, const float* b1v, const float* w2v, int o) {
    unsigned aw[4] = {a.x, a.y, a.z, a.w};
    unsigned bw[4] = {b.x, b.y, b.z, b.w};
    float r = 0.f;
#pragma unroll
    for (int i = 0; i < 4; ++i) {
        float a0 = bf2f((ushort)(aw[i] & 0xffffu));
        float a1 = bf2f((ushort)(aw[i] >> 16));
        float c0 = bf2f((ushort)(bw[i] & 0xffffu));
        float c1 = bf2f((ushort)(bw[i] >> 16));
        float h0 = fmaxf(a0 + c0 + b1v[o + 2 * i], 0.f);
        float h1 = fmaxf(a1 + c1 + b1v[o + 2 * i + 1], 0.f);
        r += h0 * w2v[o + 2 * i] + h1 * w2v[o + 2 * i + 1];
    }
    return r;
}

__global__ __launch_bounds__(256) void k_moves(const int* __restrict__ srcs,
                                               const int* __restrict__ tgts,
                                               const int* __restrict__ batch,
                                               const ushort* __restrict__ P,
                                               const float* __restrict__ b1,
                                               const float* __restrict__ W2,
                                               const float* __restrict__ b2,
                                               float* __restrict__ logits,
                                               int* __restrict__ mb,
                                               unsigned* __restrict__ segmax) {
    int tid = threadIdx.x;
    int lane = tid & 63;
    int sub = lane >> 4;   // which of 4 concurrent moves
    int ch = lane & 15;    // 16-channel slice owner

    float b1v[16], w2v[16];
    const float4* b1p = reinterpret_cast<const float4*>(b1);
    const float4* w2p = reinterpret_cast<const float4*>(W2);
#pragma unroll
    for (int q = 0; q < 4; ++q) {
        float4 bv = b1p[ch * 4 + q];
        float4 wv = w2p[ch * 4 + q];
        b1v[q * 4 + 0] = bv.x; b1v[q * 4 + 1] = bv.y; b1v[q * 4 + 2] = bv.z; b1v[q * 4 + 3] = bv.w;
        w2v[q * 4 + 0] = wv.x; w2v[q * 4 + 1] = wv.y; w2v[q * 4 + 2] = wv.z; w2v[q * 4 + 3] = wv.w;
    }
    float b2s = b2[0];

    int wid = (blockIdx.x * 256 + tid) >> 6;
    int nw = (gridDim.x * 256) >> 6;

    for (int base = wid * 8; base < NMOVES; base += nw * 8) {
        int m0 = base + sub;
        int m1 = base + 4 + sub;
        int s0 = srcs[m0], t0 = tgts[m0];
        int s1 = srcs[m1], t1 = tgts[m1];
        const uint4* pa0 = reinterpret_cast<const uint4*>(P + (size_t)s0 * 512 + ch * 16);
        const uint4* pb0 = reinterpret_cast<const uint4*>(P + (size_t)t0 * 512 + 256 + ch * 16);
        const uint4* pa1 = reinterpret_cast<const uint4*>(P + (size_t)s1 * 512 + ch * 16);
        const uint4* pb1 = reinterpret_cast<const uint4*>(P + (size_t)t1 * 512 + 256 + ch * 16);
        // issue all 8 gathers before any compute -> 8x16B in flight
        uint4 a00 = pa0[0], a01 = pa0[1];
        uint4 c00 = pb0[0], c01 = pb0[1];
        uint4 a10 = pa1[0], a11 = pa1[1];
        uint4 c10 = pb1[0], c11 = pb1[1];
        int g0 = batch[s0];
        int g1 = batch[s1];

        float p0 = dot8(a00, c00, b1v, w2v, 0) + dot8(a01, c01, b1v, w2v, 8);
        float p1 = dot8(a10, c10, b1v, w2v, 0) + dot8(a11, c11, b1v, w2v, 8);
#pragma unroll
        for (int off = 1; off < 16; off <<= 1) {
            p0 += __shfl_xor(p0, off);
            p1 += __shfl_xor(p1, off);
        }
        if (ch == 0) {
            float l0 = p0 + b2s;
            float l1 = p1 + b2s;
            logits[m0] = l0; mb[m0] = g0; atomicMax(&segmax[g0], encf(l0));
            logits[m1] = l1; mb[m1] = g1; atomicMax(&segmax[g1], encf(l1));
        }
    }
}

__global__ void k_exp(float* __restrict__ logits, const int* __restrict__ mb,
                      const unsigned* __restrict__ segmax, float* __restrict__ segsum) {
    int i = blockIdx.x * blockDim.x + threadIdx.x;
    int n = gridDim.x * blockDim.x;
    for (int m = i; m < NMOVES; m += n) {
        int g = mb[m];
        float ex = __expf(logits[m] - decf(segmax[g]));
        logits[m] = ex;
        atomicAdd(&segsum[g], ex);
    }
}

__global__ void k_norm(const float* __restrict__ ex, const int* __restrict__ mb,
                       const float* __restrict__ segsum, float* __restrict__ out) {
    int i = blockIdx.x * blockDim.x + threadIdx.x;
    int n = gridDim.x * blockDim.x;
    for (int m = i; m < NMOVES; m += n) {
        out[m] = ex[m] / (segsum[mb[m]] + 1e-16f);
    }
}

extern "C" void kernel_launch(void* const* d_in, const int* in_sizes, int n_in,
                              void* d_out, int out_size, void* d_ws, size_t ws_size,
                              hipStream_t stream) {
    const float* emb = (const float*)d_in[0];
    const int* moves = (const int*)d_in[1];
    const int* batch = (const int*)d_in[2];
    const float* W1 = (const float*)d_in[3];
    const float* b1 = (const float*)d_in[4];
    const float* W2 = (const float*)d_in[5];
    const float* b2 = (const float*)d_in[6];
    float* out = (float*)d_out;

    auto al = [](size_t x) { return (x + 255) & ~(size_t)255; };
    char* ws = (char*)d_ws;
    size_t off = 0;
    ushort* Ebf = (ushort*)(ws + off); off += al((size_t)NNODES * HID * 2);
    ushort* W1t = (ushort*)(ws + off); off += al((size_t)512 * 256 * 2);
    ushort* P   = (ushort*)(ws + off); off += al((size_t)NNODES * 512 * 2);
    float* logits = (float*)(ws + off); off += al((size_t)NMOVES * 4);
    int* mb       = (int*)(ws + off);   off += al((size_t)NMOVES * 4);
    unsigned* segmax = (unsigned*)(ws + off); off += al((size_t)NGRAPHS * 4);
    float* segsum    = (float*)(ws + off);    off += al((size_t)NGRAPHS * 4);

    k_convert_emb<<<(NNODES * HID / 8 + 255) / 256, 256, 0, stream>>>(emb, Ebf, NNODES * HID / 8);
    k_convert_w1<<<512, 256, 0, stream>>>(W1, W1t);
    k_init<<<1, 512, 0, stream>>>(segmax, segsum);

    int tiles_m = (NNODES + 127) / 128;
    k_gemm<<<tiles_m * 4, 256, 0, stream>>>(Ebf, W1t, P, NNODES);

    k_moves<<<1024, 256, 0, stream>>>(moves, moves + NMOVES, batch, P, b1, W2, b2,
                                      logits, mb, segmax);
    k_exp<<<1024, 256, 0, stream>>>(logits, mb, segmax, segsum);
    k_norm<<<1024, 256, 0, stream>>>(logits, mb, segsum, out);
}

// Round 3
// 584.802 us; speedup vs baseline: 1.0257x; 1.0002x over previous
//
#include <hip/hip_runtime.h>
#include <hip/hip_bf16.h>

#define NNODES 100000
#define HID 256
#define NMOVES 500000
#define NGRAPHS 512

typedef __attribute__((ext_vector_type(8))) short short8;
typedef __attribute__((ext_vector_type(4))) float f32x4;

#define AS_GLOBAL __attribute__((address_space(1)))
#define AS_LDS __attribute__((address_space(3)))

__device__ __forceinline__ ushort f2bf(float f) {
    unsigned u = __builtin_bit_cast(unsigned, f);
    u += 0x7FFFu + ((u >> 16) & 1u);   // round-to-nearest-even
    return (ushort)(u >> 16);
}
__device__ __forceinline__ float bf2f(ushort h) {
    unsigned u = ((unsigned)h) << 16;
    return __builtin_bit_cast(float, u);
}
// order-preserving float<->uint encoding for atomicMax
__device__ __forceinline__ unsigned encf(float f) {
    unsigned b = __builtin_bit_cast(unsigned, f);
    return (b & 0x80000000u) ? ~b : (b ^ 0x80000000u);
}
__device__ __forceinline__ float decf(unsigned u) {
    unsigned b = (u & 0x80000000u) ? (u ^ 0x80000000u) : ~u;
    return __builtin_bit_cast(float, b);
}

// ---- convert node embeddings f32 -> bf16, 8 elems/thread ----
__global__ void k_convert_emb(const float* __restrict__ src, ushort* __restrict__ dst, int total8) {
    int t = blockIdx.x * blockDim.x + threadIdx.x;
    if (t >= total8) return;
    float4 v0 = reinterpret_cast<const float4*>(src)[2 * t];
    float4 v1 = reinterpret_cast<const float4*>(src)[2 * t + 1];
    uint4 o;
    o.x = (unsigned)f2bf(v0.x) | ((unsigned)f2bf(v0.y) << 16);
    o.y = (unsigned)f2bf(v0.z) | ((unsigned)f2bf(v0.w) << 16);
    o.z = (unsigned)f2bf(v1.x) | ((unsigned)f2bf(v1.y) << 16);
    o.w = (unsigned)f2bf(v1.z) | ((unsigned)f2bf(v1.w) << 16);
    reinterpret_cast<uint4*>(dst)[t] = o;
}

// ---- build W1' transposed: W1t[n][k] ----
__global__ void k_convert_w1(const float* __restrict__ W1, ushort* __restrict__ W1t) {
    int t = blockIdx.x * blockDim.x + threadIdx.x; // 131072
    int n = t >> 8, k = t & 255;
    float v = (n < 256) ? W1[k * 256 + n] : W1[(k + 256) * 256 + (n - 256)];
    W1t[t] = f2bf(v);
}

__global__ void k_init(unsigned* __restrict__ segmax, float* __restrict__ segsum) {
    int t = threadIdx.x; // 512 threads
    segmax[t] = 0u;
    segsum[t] = 0.f;
}

// ---- P[m][n] = sum_k Ebf[m][k] * W1t[n][k]; global_load_lds staging ----
// Linear LDS [128][32] per operand (16KB total). Swapped MFMA so the 4 acc
// regs are consecutive P-columns -> one 8B packed store per fragment.
__global__ __launch_bounds__(256) void k_gemm(const ushort* __restrict__ A,
                                              const ushort* __restrict__ Bt,
                                              ushort* __restrict__ P, int M) {
    __shared__ ushort As[128 * 32];
    __shared__ ushort Bs[128 * 32];
    int bid = blockIdx.x;
    int tm = (bid >> 2) * 128;
    int tn = (bid & 3) * 128;
    int tid = threadIdx.x;
    int lane = tid & 63;
    int wave = tid >> 6;
    int wr = (wave >> 1) * 64;
    int wc = (wave & 1) * 64;

    f32x4 acc[4][4]; // acc[n][m]
#pragma unroll
    for (int n = 0; n < 4; ++n)
#pragma unroll
        for (int m = 0; m < 4; ++m) acc[n][m] = (f32x4){0.f, 0.f, 0.f, 0.f};

    // staging chunk ids: chunk c = 16B; tile has 512 chunks; wave w covers
    // [w*128, w*128+128) via two issues of 64 lanes each.
    int c0 = wave * 128 + lane;
    int c1 = c0 + 64;
    int r0 = c0 >> 2, k0 = (c0 & 3) * 8;
    int r1 = c1 >> 2, k1 = (c1 & 3) * 8;
    int ar0 = min(tm + r0, M - 1);
    int ar1 = min(tm + r1, M - 1);

    int fr = lane & 15;
    int kc = (lane >> 4) * 8;

    for (int kt = 0; kt < HID; kt += 32) {
        __syncthreads(); // all waves done reading LDS from previous iter
        __builtin_amdgcn_global_load_lds(
            (const AS_GLOBAL void*)(A + (size_t)ar0 * 256 + kt + k0),
            (AS_LDS void*)(As + (size_t)(wave * 128) * 8), 16, 0, 0);
        __builtin_amdgcn_global_load_lds(
            (const AS_GLOBAL void*)(A + (size_t)ar1 * 256 + kt + k1),
            (AS_LDS void*)(As + (size_t)(wave * 128 + 64) * 8), 16, 0, 0);
        __builtin_amdgcn_global_load_lds(
            (const AS_GLOBAL void*)(Bt + (size_t)(tn + r0) * 256 + kt + k0),
            (AS_LDS void*)(Bs + (size_t)(wave * 128) * 8), 16, 0, 0);
        __builtin_amdgcn_global_load_lds(
            (const AS_GLOBAL void*)(Bt + (size_t)(tn + r1) * 256 + kt + k1),
            (AS_LDS void*)(Bs + (size_t)(wave * 128 + 64) * 8), 16, 0, 0);
        __syncthreads(); // vmcnt(0) drained by compiler before barrier -> LDS ready

        short8 af[4], bfv[4];
#pragma unroll
        for (int m = 0; m < 4; ++m)
            af[m] = *reinterpret_cast<const short8*>(&As[(wr + m * 16 + fr) * 32 + kc]);
#pragma unroll
        for (int n = 0; n < 4; ++n)
            bfv[n] = *reinterpret_cast<const short8*>(&Bs[(wc + n * 16 + fr) * 32 + kc]);
#pragma unroll
        for (int n = 0; n < 4; ++n)
#pragma unroll
            for (int m = 0; m < 4; ++m)
                acc[n][m] = __builtin_amdgcn_mfma_f32_16x16x32_bf16(bfv[n], af[m], acc[n][m], 0, 0, 0);
    }

    // Swapped orientation: D col(lane&15) = P-row (m side), reg j = P-col (n side).
    int colj = (lane >> 4) * 4;
#pragma unroll
    for (int m = 0; m < 4; ++m) {
        int prow = tm + wr + m * 16 + fr;
        if (prow >= M) continue;
#pragma unroll
        for (int n = 0; n < 4; ++n) {
            int pcol = tn + wc + n * 16 + colj;
            uint2 pk;
            pk.x = (unsigned)f2bf(acc[n][m][0]) | ((unsigned)f2bf(acc[n][m][1]) << 16);
            pk.y = (unsigned)f2bf(acc[n][m][2]) | ((unsigned)f2bf(acc[n][m][3]) << 16);
            *reinterpret_cast<uint2*>(P + (size_t)prow * 512 + pcol) = pk;
        }
    }
}

// ---- per-move MLP tail: 16 lanes/move, 4 moves/wave, unroll x2 ----
__device__ __forceinline__ float dot8(uint4 a, uint4 b, const float* b1v, const float* w2v, int o) {
    unsigned aw[4] = {a.x, a.y, a.z, a.w};
    unsigned bw[4] = {b.x, b.y, b.z, b.w};
    float r = 0.f;
#pragma unroll
    for (int i = 0; i < 4; ++i) {
        float a0 = bf2f((ushort)(aw[i] & 0xffffu));
        float a1 = bf2f((ushort)(aw[i] >> 16));
        float c0 = bf2f((ushort)(bw[i] & 0xffffu));
        float c1 = bf2f((ushort)(bw[i] >> 16));
        float h0 = fmaxf(a0 + c0 + b1v[o + 2 * i], 0.f);
        float h1 = fmaxf(a1 + c1 + b1v[o + 2 * i + 1], 0.f);
        r += h0 * w2v[o + 2 * i] + h1 * w2v[o + 2 * i + 1];
    }
    return r;
}

__global__ __launch_bounds__(256) void k_moves(const int* __restrict__ srcs,
                                               const int* __restrict__ tgts,
                                               const int* __restrict__ batch,
                                               const ushort* __restrict__ P,
                                               const float* __restrict__ b1,
                                               const float* __restrict__ W2,
                                               const float* __restrict__ b2,
                                               float* __restrict__ logits,
                                               int* __restrict__ mb,
                                               unsigned* __restrict__ segmax) {
    int tid = threadIdx.x;
    int lane = tid & 63;
    int sub = lane >> 4;
    int ch = lane & 15;

    float b1v[16], w2v[16];
    const float4* b1p = reinterpret_cast<const float4*>(b1);
    const float4* w2p = reinterpret_cast<const float4*>(W2);
#pragma unroll
    for (int q = 0; q < 4; ++q) {
        float4 bv = b1p[ch * 4 + q];
        float4 wv = w2p[ch * 4 + q];
        b1v[q * 4 + 0] = bv.x; b1v[q * 4 + 1] = bv.y; b1v[q * 4 + 2] = bv.z; b1v[q * 4 + 3] = bv.w;
        w2v[q * 4 + 0] = wv.x; w2v[q * 4 + 1] = wv.y; w2v[q * 4 + 2] = wv.z; w2v[q * 4 + 3] = wv.w;
    }
    float b2s = b2[0];

    int wid = (blockIdx.x * 256 + tid) >> 6;
    int nw = (gridDim.x * 256) >> 6;

    for (int base = wid * 8; base < NMOVES; base += nw * 8) {
        int m0 = base + sub;
        int m1 = base + 4 + sub;
        int s0 = srcs[m0], t0 = tgts[m0];
        int s1 = srcs[m1], t1 = tgts[m1];
        const uint4* pa0 = reinterpret_cast<const uint4*>(P + (size_t)s0 * 512 + ch * 16);
        const uint4* pb0 = reinterpret_cast<const uint4*>(P + (size_t)t0 * 512 + 256 + ch * 16);
        const uint4* pa1 = reinterpret_cast<const uint4*>(P + (size_t)s1 * 512 + ch * 16);
        const uint4* pb1 = reinterpret_cast<const uint4*>(P + (size_t)t1 * 512 + 256 + ch * 16);
        uint4 a00 = pa0[0], a01 = pa0[1];
        uint4 c00 = pb0[0], c01 = pb0[1];
        uint4 a10 = pa1[0], a11 = pa1[1];
        uint4 c10 = pb1[0], c11 = pb1[1];
        int g0 = batch[s0];
        int g1 = batch[s1];

        float p0 = dot8(a00, c00, b1v, w2v, 0) + dot8(a01, c01, b1v, w2v, 8);
        float p1 = dot8(a10, c10, b1v, w2v, 0) + dot8(a11, c11, b1v, w2v, 8);
#pragma unroll
        for (int off = 1; off < 16; off <<= 1) {
            p0 += __shfl_xor(p0, off);
            p1 += __shfl_xor(p1, off);
        }
        if (ch == 0) {
            float l0 = p0 + b2s;
            float l1 = p1 + b2s;
            logits[m0] = l0; mb[m0] = g0; atomicMax(&segmax[g0], encf(l0));
            logits[m1] = l1; mb[m1] = g1; atomicMax(&segmax[g1], encf(l1));
        }
    }
}

__global__ void k_exp(float* __restrict__ logits, const int* __restrict__ mb,
                      const unsigned* __restrict__ segmax, float* __restrict__ segsum) {
    int i = blockIdx.x * blockDim.x + threadIdx.x;
    int n = gridDim.x * blockDim.x;
    for (int m = i; m < NMOVES; m += n) {
        int g = mb[m];
        float ex = __expf(logits[m] - decf(segmax[g]));
        logits[m] = ex;
        atomicAdd(&segsum[g], ex);
    }
}

__global__ void k_norm(const float* __restrict__ ex, const int* __restrict__ mb,
                       const float* __restrict__ segsum, float* __restrict__ out) {
    int i = blockIdx.x * blockDim.x + threadIdx.x;
    int n = gridDim.x * blockDim.x;
    for (int m = i; m < NMOVES; m += n) {
        out[m] = ex[m] / (segsum[mb[m]] + 1e-16f);
    }
}

extern "C" void kernel_launch(void* const* d_in, const int* in_sizes, int n_in,
                              void* d_out, int out_size, void* d_ws, size_t ws_size,
                              hipStream_t stream) {
    const float* emb = (const float*)d_in[0];
    const int* moves = (const int*)d_in[1];
    const int* batch = (const int*)d_in[2];
    const float* W1 = (const float*)d_in[3];
    const float* b1 = (const float*)d_in[4];
    const float* W2 = (const float*)d_in[5];
    const float* b2 = (const float*)d_in[6];
    float* out = (float*)d_out;

    auto al = [](size_t x) { return (x + 255) & ~(size_t)255; };
    char* ws = (char*)d_ws;
    size_t off = 0;
    ushort* Ebf = (ushort*)(ws + off); off += al((size_t)NNODES * HID * 2);
    ushort* W1t = (ushort*)(ws + off); off += al((size_t)512 * 256 * 2);
    ushort* P   = (ushort*)(ws + off); off += al((size_t)NNODES * 512 * 2);
    float* logits = (float*)(ws + off); off += al((size_t)NMOVES * 4);
    int* mb       = (int*)(ws + off);   off += al((size_t)NMOVES * 4);
    unsigned* segmax = (unsigned*)(ws + off); off += al((size_t)NGRAPHS * 4);
    float* segsum    = (float*)(ws + off);    off += al((size_t)NGRAPHS * 4);

    k_convert_emb<<<(NNODES * HID / 8 + 255) / 256, 256, 0, stream>>>(emb, Ebf, NNODES * HID / 8);
    k_convert_w1<<<512, 256, 0, stream>>>(W1, W1t);
    k_init<<<1, 512, 0, stream>>>(segmax, segsum);

    int tiles_m = (NNODES + 127) / 128;
    k_gemm<<<tiles_m * 4, 256, 0, stream>>>(Ebf, W1t, P, NNODES);

    k_moves<<<2048, 256, 0, stream>>>(moves, moves + NMOVES, batch, P, b1, W2, b2,
                                      logits, mb, segmax);
    k_exp<<<1024, 256, 0, stream>>>(logits, mb, segmax, segsum);
    k_norm<<<1024, 256, 0, stream>>>(logits, mb, segsum, out);
}

// Round 4
// 578.348 us; speedup vs baseline: 1.0372x; 1.0112x over previous
//
#include <hip/hip_runtime.h>
#include <hip/hip_bf16.h>

#define NNODES 100000
#define HID 256
#define NMOVES 500000
#define NGRAPHS 512
#define BM 64

typedef __attribute__((ext_vector_type(8))) short short8;
typedef __attribute__((ext_vector_type(4))) float f32x4;

#define AS_GLOBAL __attribute__((address_space(1)))
#define AS_LDS __attribute__((address_space(3)))

__device__ __forceinline__ unsigned f2bf(float f) {
    unsigned u = __builtin_bit_cast(unsigned, f);
    u += 0x7FFFu + ((u >> 16) & 1u);   // round-to-nearest-even
    return u >> 16;
}
__device__ __forceinline__ float bf2f(ushort h) {
    unsigned u = ((unsigned)h) << 16;
    return __builtin_bit_cast(float, u);
}
// order-preserving float<->uint encoding for atomicMax
__device__ __forceinline__ unsigned encf(float f) {
    unsigned b = __builtin_bit_cast(unsigned, f);
    return (b & 0x80000000u) ? ~b : (b ^ 0x80000000u);
}
__device__ __forceinline__ float decf(unsigned u) {
    unsigned b = (u & 0x80000000u) ? (u ^ 0x80000000u) : ~u;
    return __builtin_bit_cast(float, b);
}

// ---- build W1' transposed: W1t[n][k] ----
__global__ void k_convert_w1(const float* __restrict__ W1, ushort* __restrict__ W1t) {
    int t = blockIdx.x * blockDim.x + threadIdx.x; // 131072
    int n = t >> 8, k = t & 255;
    float v = (n < 256) ? W1[k * 256 + n] : W1[(k + 256) * 256 + (n - 256)];
    W1t[t] = (ushort)f2bf(v);
}

__global__ void k_init(unsigned* __restrict__ segmax, float* __restrict__ segsum) {
    int t = threadIdx.x; // 512 threads
    segmax[t] = 0u;
    segsum[t] = 0.f;
}

// ---- A-resident GEMM: P[m][n] = sum_k emb[m][k] * W1t[n][k] ----
// Block: 64 rows of A staged ONCE in LDS (f32->bf16 in-register, XOR-swizzled
// byte ^= (row&7)<<4). Loop 4 N-strips x 8 K-steps; per step only an 8KB B
// stage (double-buffered, gload_lds with pre-swizzled source byte ^=(row&3)<<4).
// 8 waves (2m x 4n), wave tile 32x32, swapped MFMA -> packed 8B epilogue stores.
__global__ __launch_bounds__(512, 4) void k_gemm(const float* __restrict__ emb,
                                                 const ushort* __restrict__ Bt,
                                                 ushort* __restrict__ P, int M) {
    __shared__ __align__(16) ushort Asm[BM * 256];      // 32 KB
    __shared__ __align__(16) ushort Bsm[2][128 * 32];   // 2 x 8 KB
    int tid = threadIdx.x;
    int lane = tid & 63;
    int wave = tid >> 6;
    int tm = blockIdx.x * BM;
    int wm = wave >> 2;   // 0..1  (32-row group)
    int wn = wave & 3;    // 0..3  (32-col group within strip)
    int fr = lane & 15;
    int q = lane >> 4;    // 0..3

    // ---- stage A panel: 64 rows x 256 k, convert f32->bf16, swizzled write ----
#pragma unroll
    for (int it = 0; it < 4; ++it) {
        int c = it * 512 + tid;          // chunk 0..2047 (16B chunks)
        int row = c >> 5;                // 0..63
        int j = c & 31;                  // k-chunk within row
        int grow = tm + row;
        if (grow >= M) grow = M - 1;
        const float4* sp = reinterpret_cast<const float4*>(emb + (size_t)grow * 256 + j * 8);
        float4 v0 = sp[0], v1 = sp[1];
        uint4 o;
        o.x = f2bf(v0.x) | (f2bf(v0.y) << 16);
        o.y = f2bf(v0.z) | (f2bf(v0.w) << 16);
        o.z = f2bf(v1.x) | (f2bf(v1.y) << 16);
        o.w = f2bf(v1.z) | (f2bf(v1.w) << 16);
        int dst = row * 512 + ((j ^ (row & 7)) << 4);   // byte offset
        *reinterpret_cast<uint4*>(reinterpret_cast<char*>(Asm) + dst) = o;
    }
    // ---- stage B[g=0]: strip 0, kstep 0 (8 KB = 512 threads x 16B) ----
    {
        int row = tid >> 2, j = tid & 3;
        const ushort* src = Bt + (size_t)row * 256 + ((j ^ (row & 3)) << 3);
        __builtin_amdgcn_global_load_lds((const AS_GLOBAL void*)src,
            (AS_LDS void*)(reinterpret_cast<char*>(&Bsm[0][0]) + wave * 1024), 16, 0, 0);
    }
    __syncthreads();

    f32x4 acc[2][2]; // [nn][mm]
#pragma unroll
    for (int n = 0; n < 2; ++n)
#pragma unroll
        for (int m = 0; m < 2; ++m) acc[n][m] = (f32x4){0.f, 0.f, 0.f, 0.f};

    const char* Ab = reinterpret_cast<const char*>(Asm);

    for (int g = 0; g < 32; ++g) {
        int kt = g & 7;
        int buf = g & 1;
        if (g < 31) { // prefetch next B k-step into other buffer
            int g2 = g + 1;
            int r2 = g2 >> 3, kt2 = g2 & 7;
            int row = tid >> 2, j = tid & 3;
            const ushort* src = Bt + (size_t)(r2 * 128 + row) * 256 + kt2 * 32 + ((j ^ (row & 3)) << 3);
            __builtin_amdgcn_global_load_lds((const AS_GLOBAL void*)src,
                (AS_LDS void*)(reinterpret_cast<char*>(&Bsm[buf ^ 1][0]) + wave * 1024), 16, 0, 0);
        }
        const char* Bb = reinterpret_cast<const char*>(&Bsm[buf][0]);

        short8 af[2], bfv[2];
#pragma unroll
        for (int m = 0; m < 2; ++m) {
            int row = wm * 32 + m * 16 + fr;
            int abyte = row * 512 + (((kt * 4 + q) ^ (fr & 7)) << 4);
            af[m] = *reinterpret_cast<const short8*>(Ab + abyte);
        }
#pragma unroll
        for (int n = 0; n < 2; ++n) {
            int row = wn * 32 + n * 16 + fr;
            int bbyte = row * 64 + ((q ^ (fr & 3)) << 4);
            bfv[n] = *reinterpret_cast<const short8*>(Bb + bbyte);
        }
#pragma unroll
        for (int n = 0; n < 2; ++n)
#pragma unroll
            for (int m = 0; m < 2; ++m)
                acc[n][m] = __builtin_amdgcn_mfma_f32_16x16x32_bf16(bfv[n], af[m], acc[n][m], 0, 0, 0);

        if (kt == 7) { // end of N-strip: write out, reset acc
            int r = g >> 3;
#pragma unroll
            for (int m = 0; m < 2; ++m) {
                int prow = tm + wm * 32 + m * 16 + fr;
                if (prow < M) {
#pragma unroll
                    for (int n = 0; n < 2; ++n) {
                        int pcol = r * 128 + wn * 32 + n * 16 + q * 4;
                        uint2 pk;
                        pk.x = f2bf(acc[n][m][0]) | (f2bf(acc[n][m][1]) << 16);
                        pk.y = f2bf(acc[n][m][2]) | (f2bf(acc[n][m][3]) << 16);
                        *reinterpret_cast<uint2*>(P + (size_t)prow * 512 + pcol) = pk;
                    }
                }
            }
#pragma unroll
            for (int n = 0; n < 2; ++n)
#pragma unroll
                for (int m = 0; m < 2; ++m) acc[n][m] = (f32x4){0.f, 0.f, 0.f, 0.f};
        }
        __syncthreads();
    }
}

// ---- per-move MLP tail: 16 lanes/move, 4 moves/wave, unroll x2 ----
__device__ __forceinline__ float dot8(uint4 a, uint4 b, const float* b1v, const float* w2v, int o) {
    unsigned aw[4] = {a.x, a.y, a.z, a.w};
    unsigned bw[4] = {b.x, b.y, b.z, b.w};
    float r = 0.f;
#pragma unroll
    for (int i = 0; i < 4; ++i) {
        float a0 = bf2f((ushort)(aw[i] & 0xffffu));
        float a1 = bf2f((ushort)(aw[i] >> 16));
        float c0 = bf2f((ushort)(bw[i] & 0xffffu));
        float c1 = bf2f((ushort)(bw[i] >> 16));
        float h0 = fmaxf(a0 + c0 + b1v[o + 2 * i], 0.f);
        float h1 = fmaxf(a1 + c1 + b1v[o + 2 * i + 1], 0.f);
        r += h0 * w2v[o + 2 * i] + h1 * w2v[o + 2 * i + 1];
    }
    return r;
}

__global__ __launch_bounds__(256) void k_moves(const int* __restrict__ srcs,
                                               const int* __restrict__ tgts,
                                               const int* __restrict__ batch,
                                               const ushort* __restrict__ P,
                                               const float* __restrict__ b1,
                                               const float* __restrict__ W2,
                                               const float* __restrict__ b2,
                                               float* __restrict__ logits,
                                               int* __restrict__ mb,
                                               unsigned* __restrict__ segmax) {
    int tid = threadIdx.x;
    int lane = tid & 63;
    int sub = lane >> 4;
    int ch = lane & 15;

    float b1v[16], w2v[16];
    const float4* b1p = reinterpret_cast<const float4*>(b1);
    const float4* w2p = reinterpret_cast<const float4*>(W2);
#pragma unroll
    for (int q = 0; q < 4; ++q) {
        float4 bv = b1p[ch * 4 + q];
        float4 wv = w2p[ch * 4 + q];
        b1v[q * 4 + 0] = bv.x; b1v[q * 4 + 1] = bv.y; b1v[q * 4 + 2] = bv.z; b1v[q * 4 + 3] = bv.w;
        w2v[q * 4 + 0] = wv.x; w2v[q * 4 + 1] = wv.y; w2v[q * 4 + 2] = wv.z; w2v[q * 4 + 3] = wv.w;
    }
    float b2s = b2[0];

    int wid = (blockIdx.x * 256 + tid) >> 6;
    int nw = (gridDim.x * 256) >> 6;

    for (int base = wid * 8; base < NMOVES; base += nw * 8) {
        int m0 = base + sub;
        int m1 = base + 4 + sub;
        int s0 = srcs[m0], t0 = tgts[m0];
        int s1 = srcs[m1], t1 = tgts[m1];
        const uint4* pa0 = reinterpret_cast<const uint4*>(P + (size_t)s0 * 512 + ch * 16);
        const uint4* pb0 = reinterpret_cast<const uint4*>(P + (size_t)t0 * 512 + 256 + ch * 16);
        const uint4* pa1 = reinterpret_cast<const uint4*>(P + (size_t)s1 * 512 + ch * 16);
        const uint4* pb1 = reinterpret_cast<const uint4*>(P + (size_t)t1 * 512 + 256 + ch * 16);
        uint4 a00 = pa0[0], a01 = pa0[1];
        uint4 c00 = pb0[0], c01 = pb0[1];
        uint4 a10 = pa1[0], a11 = pa1[1];
        uint4 c10 = pb1[0], c11 = pb1[1];
        int g0 = batch[s0];
        int g1 = batch[s1];

        float p0 = dot8(a00, c00, b1v, w2v, 0) + dot8(a01, c01, b1v, w2v, 8);
        float p1 = dot8(a10, c10, b1v, w2v, 0) + dot8(a11, c11, b1v, w2v, 8);
#pragma unroll
        for (int off = 1; off < 16; off <<= 1) {
            p0 += __shfl_xor(p0, off);
            p1 += __shfl_xor(p1, off);
        }
        if (ch == 0) {
            float l0 = p0 + b2s;
            float l1 = p1 + b2s;
            logits[m0] = l0; mb[m0] = g0; atomicMax(&segmax[g0], encf(l0));
            logits[m1] = l1; mb[m1] = g1; atomicMax(&segmax[g1], encf(l1));
        }
    }
}

__global__ void k_exp(float* __restrict__ logits, const int* __restrict__ mb,
                      const unsigned* __restrict__ segmax, float* __restrict__ segsum) {
    int i = blockIdx.x * blockDim.x + threadIdx.x;
    int n = gridDim.x * blockDim.x;
    for (int m = i; m < NMOVES; m += n) {
        int g = mb[m];
        float ex = __expf(logits[m] - decf(segmax[g]));
        logits[m] = ex;
        atomicAdd(&segsum[g], ex);
    }
}

__global__ void k_norm(const float* __restrict__ ex, const int* __restrict__ mb,
                       const float* __restrict__ segsum, float* __restrict__ out) {
    int i = blockIdx.x * blockDim.x + threadIdx.x;
    int n = gridDim.x * blockDim.x;
    for (int m = i; m < NMOVES; m += n) {
        out[m] = ex[m] / (segsum[mb[m]] + 1e-16f);
    }
}

extern "C" void kernel_launch(void* const* d_in, const int* in_sizes, int n_in,
                              void* d_out, int out_size, void* d_ws, size_t ws_size,
                              hipStream_t stream) {
    const float* emb = (const float*)d_in[0];
    const int* moves = (const int*)d_in[1];
    const int* batch = (const int*)d_in[2];
    const float* W1 = (const float*)d_in[3];
    const float* b1 = (const float*)d_in[4];
    const float* W2 = (const float*)d_in[5];
    const float* b2 = (const float*)d_in[6];
    float* out = (float*)d_out;

    auto al = [](size_t x) { return (x + 255) & ~(size_t)255; };
    char* ws = (char*)d_ws;
    size_t off = 0;
    ushort* W1t = (ushort*)(ws + off); off += al((size_t)512 * 256 * 2);
    ushort* P   = (ushort*)(ws + off); off += al((size_t)NNODES * 512 * 2);
    float* logits = (float*)(ws + off); off += al((size_t)NMOVES * 4);
    int* mb       = (int*)(ws + off);   off += al((size_t)NMOVES * 4);
    unsigned* segmax = (unsigned*)(ws + off); off += al((size_t)NGRAPHS * 4);
    float* segsum    = (float*)(ws + off);    off += al((size_t)NGRAPHS * 4);

    k_convert_w1<<<512, 256, 0, stream>>>(W1, W1t);
    k_init<<<1, 512, 0, stream>>>(segmax, segsum);

    int tiles_m = (NNODES + BM - 1) / BM;   // 1563
    k_gemm<<<tiles_m, 512, 0, stream>>>(emb, W1t, P, NNODES);

    k_moves<<<2048, 256, 0, stream>>>(moves, moves + NMOVES, batch, P, b1, W2, b2,
                                      logits, mb, segmax);
    k_exp<<<1024, 256, 0, stream>>>(logits, mb, segmax, segsum);
    k_norm<<<1024, 256, 0, stream>>>(logits, mb, segsum, out);
}

// Round 5
// 249.834 us; speedup vs baseline: 2.4010x; 2.3149x over previous
//
#include <hip/hip_runtime.h>
#include <hip/hip_bf16.h>

#define NNODES 100000
#define HID 256
#define NMOVES 500000
#define NGRAPHS 512
#define BM 64
#define PB 128   // partial-reduction blocks

typedef __attribute__((ext_vector_type(8))) short short8;
typedef __attribute__((ext_vector_type(4))) float f32x4;

#define AS_GLOBAL __attribute__((address_space(1)))
#define AS_LDS __attribute__((address_space(3)))

__device__ __forceinline__ unsigned f2bf(float f) {
    unsigned u = __builtin_bit_cast(unsigned, f);
    u += 0x7FFFu + ((u >> 16) & 1u);   // round-to-nearest-even
    return u >> 16;
}
__device__ __forceinline__ float bf2f(ushort h) {
    unsigned u = ((unsigned)h) << 16;
    return __builtin_bit_cast(float, u);
}
// order-preserving float<->uint encoding for max
__device__ __forceinline__ unsigned encf(float f) {
    unsigned b = __builtin_bit_cast(unsigned, f);
    return (b & 0x80000000u) ? ~b : (b ^ 0x80000000u);
}
__device__ __forceinline__ float decf(unsigned u) {
    unsigned b = (u & 0x80000000u) ? (u ^ 0x80000000u) : ~u;
    return __builtin_bit_cast(float, b);
}

// ---- build W1' transposed: W1t[n][k] ----
__global__ void k_convert_w1(const float* __restrict__ W1, ushort* __restrict__ W1t) {
    int t = blockIdx.x * blockDim.x + threadIdx.x; // 131072
    int n = t >> 8, k = t & 255;
    float v = (n < 256) ? W1[k * 256 + n] : W1[(k + 256) * 256 + (n - 256)];
    W1t[t] = (ushort)f2bf(v);
}

// ---- A-resident GEMM (unchanged from R4): P = emb @ [W1_top | W1_bot] ----
__global__ __launch_bounds__(512, 4) void k_gemm(const float* __restrict__ emb,
                                                 const ushort* __restrict__ Bt,
                                                 ushort* __restrict__ P, int M) {
    __shared__ __align__(16) ushort Asm[BM * 256];      // 32 KB
    __shared__ __align__(16) ushort Bsm[2][128 * 32];   // 2 x 8 KB
    int tid = threadIdx.x;
    int lane = tid & 63;
    int wave = tid >> 6;
    int tm = blockIdx.x * BM;
    int wm = wave >> 2;
    int wn = wave & 3;
    int fr = lane & 15;
    int q = lane >> 4;

#pragma unroll
    for (int it = 0; it < 4; ++it) {
        int c = it * 512 + tid;
        int row = c >> 5;
        int j = c & 31;
        int grow = tm + row;
        if (grow >= M) grow = M - 1;
        const float4* sp = reinterpret_cast<const float4*>(emb + (size_t)grow * 256 + j * 8);
        float4 v0 = sp[0], v1 = sp[1];
        uint4 o;
        o.x = f2bf(v0.x) | (f2bf(v0.y) << 16);
        o.y = f2bf(v0.z) | (f2bf(v0.w) << 16);
        o.z = f2bf(v1.x) | (f2bf(v1.y) << 16);
        o.w = f2bf(v1.z) | (f2bf(v1.w) << 16);
        int dst = row * 512 + ((j ^ (row & 7)) << 4);
        *reinterpret_cast<uint4*>(reinterpret_cast<char*>(Asm) + dst) = o;
    }
    {
        int row = tid >> 2, j = tid & 3;
        const ushort* src = Bt + (size_t)row * 256 + ((j ^ (row & 3)) << 3);
        __builtin_amdgcn_global_load_lds((const AS_GLOBAL void*)src,
            (AS_LDS void*)(reinterpret_cast<char*>(&Bsm[0][0]) + wave * 1024), 16, 0, 0);
    }
    __syncthreads();

    f32x4 acc[2][2];
#pragma unroll
    for (int n = 0; n < 2; ++n)
#pragma unroll
        for (int m = 0; m < 2; ++m) acc[n][m] = (f32x4){0.f, 0.f, 0.f, 0.f};

    const char* Ab = reinterpret_cast<const char*>(Asm);

    for (int g = 0; g < 32; ++g) {
        int kt = g & 7;
        int buf = g & 1;
        if (g < 31) {
            int g2 = g + 1;
            int r2 = g2 >> 3, kt2 = g2 & 7;
            int row = tid >> 2, j = tid & 3;
            const ushort* src = Bt + (size_t)(r2 * 128 + row) * 256 + kt2 * 32 + ((j ^ (row & 3)) << 3);
            __builtin_amdgcn_global_load_lds((const AS_GLOBAL void*)src,
                (AS_LDS void*)(reinterpret_cast<char*>(&Bsm[buf ^ 1][0]) + wave * 1024), 16, 0, 0);
        }
        const char* Bb = reinterpret_cast<const char*>(&Bsm[buf][0]);

        short8 af[2], bfv[2];
#pragma unroll
        for (int m = 0; m < 2; ++m) {
            int row = wm * 32 + m * 16 + fr;
            int abyte = row * 512 + (((kt * 4 + q) ^ (fr & 7)) << 4);
            af[m] = *reinterpret_cast<const short8*>(Ab + abyte);
        }
#pragma unroll
        for (int n = 0; n < 2; ++n) {
            int row = wn * 32 + n * 16 + fr;
            int bbyte = row * 64 + ((q ^ (fr & 3)) << 4);
            bfv[n] = *reinterpret_cast<const short8*>(Bb + bbyte);
        }
#pragma unroll
        for (int n = 0; n < 2; ++n)
#pragma unroll
            for (int m = 0; m < 2; ++m)
                acc[n][m] = __builtin_amdgcn_mfma_f32_16x16x32_bf16(bfv[n], af[m], acc[n][m], 0, 0, 0);

        if (kt == 7) {
            int r = g >> 3;
#pragma unroll
            for (int m = 0; m < 2; ++m) {
                int prow = tm + wm * 32 + m * 16 + fr;
                if (prow < M) {
#pragma unroll
                    for (int n = 0; n < 2; ++n) {
                        int pcol = r * 128 + wn * 32 + n * 16 + q * 4;
                        uint2 pk;
                        pk.x = f2bf(acc[n][m][0]) | (f2bf(acc[n][m][1]) << 16);
                        pk.y = f2bf(acc[n][m][2]) | (f2bf(acc[n][m][3]) << 16);
                        *reinterpret_cast<uint2*>(P + (size_t)prow * 512 + pcol) = pk;
                    }
                }
            }
#pragma unroll
            for (int n = 0; n < 2; ++n)
#pragma unroll
                for (int m = 0; m < 2; ++m) acc[n][m] = (f32x4){0.f, 0.f, 0.f, 0.f};
        }
        __syncthreads();
    }
}

// ---- per-move MLP tail: 16 lanes/move, 4 moves/wave, unroll x2. NO atomics ----
__device__ __forceinline__ float dot8(uint4 a, uint4 b, const float* b1v, const float* w2v, int o) {
    unsigned aw[4] = {a.x, a.y, a.z, a.w};
    unsigned bw[4] = {b.x, b.y, b.z, b.w};
    float r = 0.f;
#pragma unroll
    for (int i = 0; i < 4; ++i) {
        float a0 = bf2f((ushort)(aw[i] & 0xffffu));
        float a1 = bf2f((ushort)(aw[i] >> 16));
        float c0 = bf2f((ushort)(bw[i] & 0xffffu));
        float c1 = bf2f((ushort)(bw[i] >> 16));
        float h0 = fmaxf(a0 + c0 + b1v[o + 2 * i], 0.f);
        float h1 = fmaxf(a1 + c1 + b1v[o + 2 * i + 1], 0.f);
        r += h0 * w2v[o + 2 * i] + h1 * w2v[o + 2 * i + 1];
    }
    return r;
}

__global__ __launch_bounds__(256) void k_moves(const int* __restrict__ srcs,
                                               const int* __restrict__ tgts,
                                               const int* __restrict__ batch,
                                               const ushort* __restrict__ P,
                                               const float* __restrict__ b1,
                                               const float* __restrict__ W2,
                                               const float* __restrict__ b2,
                                               float* __restrict__ logits,
                                               int* __restrict__ mb) {
    int tid = threadIdx.x;
    int lane = tid & 63;
    int sub = lane >> 4;
    int ch = lane & 15;

    float b1v[16], w2v[16];
    const float4* b1p = reinterpret_cast<const float4*>(b1);
    const float4* w2p = reinterpret_cast<const float4*>(W2);
#pragma unroll
    for (int q = 0; q < 4; ++q) {
        float4 bv = b1p[ch * 4 + q];
        float4 wv = w2p[ch * 4 + q];
        b1v[q * 4 + 0] = bv.x; b1v[q * 4 + 1] = bv.y; b1v[q * 4 + 2] = bv.z; b1v[q * 4 + 3] = bv.w;
        w2v[q * 4 + 0] = wv.x; w2v[q * 4 + 1] = wv.y; w2v[q * 4 + 2] = wv.z; w2v[q * 4 + 3] = wv.w;
    }
    float b2s = b2[0];

    int wid = (blockIdx.x * 256 + tid) >> 6;
    int nw = (gridDim.x * 256) >> 6;

    for (int base = wid * 8; base < NMOVES; base += nw * 8) {
        int m0 = base + sub;
        int m1 = base + 4 + sub;
        int s0 = srcs[m0], t0 = tgts[m0];
        int s1 = srcs[m1], t1 = tgts[m1];
        const uint4* pa0 = reinterpret_cast<const uint4*>(P + (size_t)s0 * 512 + ch * 16);
        const uint4* pb0 = reinterpret_cast<const uint4*>(P + (size_t)t0 * 512 + 256 + ch * 16);
        const uint4* pa1 = reinterpret_cast<const uint4*>(P + (size_t)s1 * 512 + ch * 16);
        const uint4* pb1 = reinterpret_cast<const uint4*>(P + (size_t)t1 * 512 + 256 + ch * 16);
        uint4 a00 = pa0[0], a01 = pa0[1];
        uint4 c00 = pb0[0], c01 = pb0[1];
        uint4 a10 = pa1[0], a11 = pa1[1];
        uint4 c10 = pb1[0], c11 = pb1[1];
        int g0 = batch[s0];
        int g1 = batch[s1];

        float p0 = dot8(a00, c00, b1v, w2v, 0) + dot8(a01, c01, b1v, w2v, 8);
        float p1 = dot8(a10, c10, b1v, w2v, 0) + dot8(a11, c11, b1v, w2v, 8);
#pragma unroll
        for (int off = 1; off < 16; off <<= 1) {
            p0 += __shfl_xor(p0, off);
            p1 += __shfl_xor(p1, off);
        }
        if (ch == 0) {
            logits[m0] = p0 + b2s; mb[m0] = g0;
            logits[m1] = p1 + b2s; mb[m1] = g1;
        }
    }
}

// ---- per-block segment partials: LDS max + LDS sum, non-atomic global flush ----
__global__ __launch_bounds__(256) void k_part(const float* __restrict__ logits,
                                              const int* __restrict__ mb,
                                              float* __restrict__ pmax,
                                              float* __restrict__ psum) {
    __shared__ unsigned lmax[NGRAPHS];
    __shared__ float lsum[NGRAPHS];
    int tid = threadIdx.x;
    lmax[tid] = 0u; lmax[tid + 256] = 0u;
    lsum[tid] = 0.f; lsum[tid + 256] = 0.f;
    __syncthreads();

    int stride = PB * 256;
    for (int m = blockIdx.x * 256 + tid; m < NMOVES; m += stride)
        atomicMax(&lmax[mb[m]], encf(logits[m]));
    __syncthreads();
    for (int m = blockIdx.x * 256 + tid; m < NMOVES; m += stride) {
        int g = mb[m];
        atomicAdd(&lsum[g], __expf(logits[m] - decf(lmax[g])));
    }
    __syncthreads();

#pragma unroll
    for (int i = 0; i < 2; ++i) {
        int s = tid + i * 256;
        unsigned e = lmax[s];
        pmax[blockIdx.x * NGRAPHS + s] = (e == 0u) ? -INFINITY : decf(e);
        psum[blockIdx.x * NGRAPHS + s] = lsum[s];
    }
}

// ---- fold PB partials per segment -> global max, 1/(sum+eps) ----
__global__ void k_combine(const float* __restrict__ pmax, const float* __restrict__ psum,
                          float* __restrict__ gmax, float* __restrict__ ginv) {
    int s = threadIdx.x; // 512
    float M = -INFINITY;
#pragma unroll 4
    for (int b = 0; b < PB; ++b) M = fmaxf(M, pmax[b * NGRAPHS + s]);
    float S = 0.f;
#pragma unroll 4
    for (int b = 0; b < PB; ++b) {
        float pm = pmax[b * NGRAPHS + s];
        float ps = psum[b * NGRAPHS + s];
        if (ps > 0.f) S += ps * __expf(pm - M);
    }
    gmax[s] = M;
    ginv[s] = 1.f / (S + 1e-16f);
}

__global__ void k_norm(const float* __restrict__ logits, const int* __restrict__ mb,
                       const float* __restrict__ gmax, const float* __restrict__ ginv,
                       float* __restrict__ out) {
    int i = blockIdx.x * blockDim.x + threadIdx.x;
    int n = gridDim.x * blockDim.x;
    for (int m = i; m < NMOVES; m += n) {
        int g = mb[m];
        out[m] = __expf(logits[m] - gmax[g]) * ginv[g];
    }
}

extern "C" void kernel_launch(void* const* d_in, const int* in_sizes, int n_in,
                              void* d_out, int out_size, void* d_ws, size_t ws_size,
                              hipStream_t stream) {
    const float* emb = (const float*)d_in[0];
    const int* moves = (const int*)d_in[1];
    const int* batch = (const int*)d_in[2];
    const float* W1 = (const float*)d_in[3];
    const float* b1 = (const float*)d_in[4];
    const float* W2 = (const float*)d_in[5];
    const float* b2 = (const float*)d_in[6];
    float* out = (float*)d_out;

    auto al = [](size_t x) { return (x + 255) & ~(size_t)255; };
    char* ws = (char*)d_ws;
    size_t off = 0;
    ushort* W1t = (ushort*)(ws + off); off += al((size_t)512 * 256 * 2);
    ushort* P   = (ushort*)(ws + off); off += al((size_t)NNODES * 512 * 2);
    float* logits = (float*)(ws + off); off += al((size_t)NMOVES * 4);
    int* mb       = (int*)(ws + off);   off += al((size_t)NMOVES * 4);
    float* pmax   = (float*)(ws + off); off += al((size_t)PB * NGRAPHS * 4);
    float* psum   = (float*)(ws + off); off += al((size_t)PB * NGRAPHS * 4);
    float* gmax   = (float*)(ws + off); off += al((size_t)NGRAPHS * 4);
    float* ginv   = (float*)(ws + off); off += al((size_t)NGRAPHS * 4);

    k_convert_w1<<<512, 256, 0, stream>>>(W1, W1t);

    int tiles_m = (NNODES + BM - 1) / BM;   // 1563
    k_gemm<<<tiles_m, 512, 0, stream>>>(emb, W1t, P, NNODES);

    k_moves<<<2048, 256, 0, stream>>>(moves, moves + NMOVES, batch, P, b1, W2, b2,
                                      logits, mb);
    k_part<<<PB, 256, 0, stream>>>(logits, mb, pmax, psum);
    k_combine<<<1, NGRAPHS, 0, stream>>>(pmax, psum, gmax, ginv);
    k_norm<<<1024, 256, 0, stream>>>(logits, mb, gmax, ginv, out);
}